// Round 3
// baseline (460.805 us; speedup 1.0000x reference)
//
#include <hip/hip_runtime.h>

#define T       512
#define DIN     32
#define HCELLS  64
#define NB      16      // batch elems per block (MFMA N dim)
#define NSLICE  64      // 1024 / NB
#define TB      256     // pipeline kernel: 4 waves (one layer per block)
#define CH      16      // chunk steps per cross-block handoff
#define NCH     (T / CH)

typedef _Float16 half8  __attribute__((ext_vector_type(8)));
typedef _Float16 half4v __attribute__((ext_vector_type(4)));
typedef float    float4v __attribute__((ext_vector_type(4)));

#define STRH    72      // h rows: 64 + 8 pad (halfs)
#define SB_HALFS (2*16*STRH)        // one layer's double-buffered h state

#define LOG2E   1.44269504f
#define SLOG2E  2.88539008f     // 2*log2(e); cell state kept as cs = SLOG2E * c

// Raw barrier: orders LDS but leaves global loads/stores in flight.
#define BARRIER() asm volatile("s_waitcnt lgkmcnt(0)\n\ts_barrier" ::: "memory")

// workspace layout
#define WS_FLAG_BYTES 4096
#define H0T   (16 * HCELLS)                  // halfs per step per slice
#define H0S   ((size_t)T * H0T)              // halfs per slice
#define WS_NEED (WS_FLAG_BYTES + (size_t)NSLICE * H0S * sizeof(_Float16))

__device__ __forceinline__ int hidx(int p, int n, int k) { return (p * 16 + n) * STRH + k; }

__device__ __forceinline__ void cvt8(const float* v, half8& hi) {
    #pragma unroll
    for (int e = 0; e < 8; ++e) hi[e] = (_Float16)v[e];
}

// Scaled-domain LSTM cell update (gate scales folded into weights):
//   acc[0]=-log2e*zi, acc[1]=-log2e*zf, acc[2]=2log2e*zg, acc[3]=-log2e*zo ; cs = 2log2e*c
__device__ __forceinline__ void cell_update(const float4v acc[4], float* cs,
                                            half4v& hh, float* hout)
{
    #pragma unroll
    for (int r = 0; r < 4; ++r) {
        float ei = __builtin_amdgcn_exp2f(acc[0][r]);   // e^{-zi}
        float ef = __builtin_amdgcn_exp2f(acc[1][r]);   // e^{-zf}
        float G2 = __builtin_amdgcn_exp2f(acc[2][r]);   // e^{2 zg}
        float I  = 1.0f + ei, F = 1.0f + ef;
        float Gp = 1.0f + G2;
        float Gms = fmaf(SLOG2E, G2, -SLOG2E);          // s*(G2-1)
        float P   = I * Gp;
        float num = fmaf(F, Gms, cs[r] * P);
        float csn = num * __builtin_amdgcn_rcpf(F * P);
        csn = fminf(fmaxf(csn, -50.0f), 50.0f);
        cs[r] = csn;
        float eo = __builtin_amdgcn_exp2f(acc[3][r]);   // e^{-zo}
        float C2 = __builtin_amdgcn_exp2f(csn);         // e^{2 c'}
        float O  = 1.0f + eo;
        float Cp = 1.0f + C2, Cm = C2 - 1.0f;
        float h  = Cm * __builtin_amdgcn_rcpf(O * Cp);
        if (hout) hout[r] = h;
        hh[r] = (_Float16)h;
    }
}

// ======================= pipelined 2-stage kernel (128 blocks) =======================
// block g: role = (g>>3)&1 (0=L0 producer, 1=L1 consumer), slice = ((g>>4)<<3)|(g&7).
// Pair (g, g+8) shares a slice and (under blockid%8 XCD round-robin) an XCD L2.
__global__ void __launch_bounds__(TB, 1)
lstm2_pipe_kernel(const float* __restrict__ x,
                  const float* __restrict__ Wih0, const float* __restrict__ Whh0,
                  const float* __restrict__ bih0, const float* __restrict__ bhh0,
                  const float* __restrict__ Wih1, const float* __restrict__ Whh1,
                  const float* __restrict__ bih1, const float* __restrict__ bhh1,
                  const float* __restrict__ W1,   const float* __restrict__ b1,
                  const float* __restrict__ W2,   const float* __restrict__ b2,
                  unsigned* __restrict__ prog, _Float16* __restrict__ h0g,
                  float* __restrict__ out)
{
    const int tid  = threadIdx.x;
    const int wl   = tid >> 6;          // wave 0..3: hidden slice wl*16..wl*16+15
    const int lane = tid & 63;
    const int n16  = lane & 15;         // MFMA free index / local batch
    const int q    = lane >> 4;         // quad 0..3
    const int j0   = wl * 16 + q * 4;   // hidden-unit base (4 rows)

    const int g     = blockIdx.x;
    const int role  = (g >> 3) & 1;
    const int slice = ((g >> 4) << 3) | (g & 7);
    const int b0    = slice * NB;

    __shared__ __align__(16) _Float16 SB[SB_HALFS];
    __shared__ __align__(16) float HS[16 * 68 + 16 * 33];

    const float gsc[4] = {-LOG2E, -LOG2E, SLOG2E, -LOG2E};

    // ---------------- per-role weight fragments (single fp16) ----------------
    half8 ah[4][4];
    float4v biasv[4];

    #pragma unroll
    for (int l = 0; l < 4; ++l) {
        const int row = (l * 4 + wl) * 16 + n16;
        const float g2 = gsc[l];
        float v[8];
        if (role == 0) {
            {
                const float4* p = (const float4*)(Wih0 + row * DIN + q * 8);
                float4 u0 = p[0], u1 = p[1];
                v[0]=g2*u0.x; v[1]=g2*u0.y; v[2]=g2*u0.z; v[3]=g2*u0.w;
                v[4]=g2*u1.x; v[5]=g2*u1.y; v[6]=g2*u1.z; v[7]=g2*u1.w;
                cvt8(v, ah[l][0]);
            }
            #pragma unroll
            for (int kt = 1; kt < 3; ++kt) {
                const float4* p = (const float4*)(Whh0 + row * HCELLS + (kt - 1) * 32 + q * 8);
                float4 u0 = p[0], u1 = p[1];
                v[0]=g2*u0.x; v[1]=g2*u0.y; v[2]=g2*u0.z; v[3]=g2*u0.w;
                v[4]=g2*u1.x; v[5]=g2*u1.y; v[6]=g2*u1.z; v[7]=g2*u1.w;
                cvt8(v, ah[l][kt]);
            }
            const int r0 = l * 64 + j0;
            float4v bi = *(const float4v*)(bih0 + r0);
            float4v bh = *(const float4v*)(bhh0 + r0);
            biasv[l] = (bi + bh) * g2;
        } else {
            #pragma unroll
            for (int kt = 0; kt < 4; ++kt) {
                const float* base = (kt < 2) ? (Wih1 + row * HCELLS + kt * 32)
                                             : (Whh1 + row * HCELLS + (kt - 2) * 32);
                const float4* p = (const float4*)(base + q * 8);
                float4 u0 = p[0], u1 = p[1];
                v[0]=g2*u0.x; v[1]=g2*u0.y; v[2]=g2*u0.z; v[3]=g2*u0.w;
                v[4]=g2*u1.x; v[5]=g2*u1.y; v[6]=g2*u1.z; v[7]=g2*u1.w;
                cvt8(v, ah[l][kt]);
            }
            const int r0 = l * 64 + j0;
            float4v bi = *(const float4v*)(bih1 + r0);
            float4v bh = *(const float4v*)(bhh1 + r0);
            biasv[l] = (bi + bh) * g2;
        }
    }

    // zero the h double-buffer (h(-1) = 0)
    for (int i = tid; i < SB_HALFS / 2; i += TB) ((int*)SB)[i] = 0;
    __syncthreads();

    float cs[4] = {0, 0, 0, 0};
    float hlast[4];

    if (role == 0) {
        // ======================= producer: layer 0 =======================
        const float* xq = x + ((size_t)(b0 + n16) * T) * DIN + q * 8;
        float4 xn0 = ((const float4*)xq)[0];
        float4 xn1 = ((const float4*)xq)[1];
        xq += DIN;

        _Float16* hstream = h0g + (size_t)slice * H0S + n16 * HCELLS + j0;

        for (int t = 0; t < T; ++t) {
            const int pr = t & 1, pw = pr ^ 1;

            float4 xc0 = xn0, xc1 = xn1;
            if (t + 1 < T) { xn0 = ((const float4*)xq)[0]; xn1 = ((const float4*)xq)[1]; xq += DIN; }

            half8 bhx;
            bhx[0]=(_Float16)xc0.x; bhx[1]=(_Float16)xc0.y; bhx[2]=(_Float16)xc0.z; bhx[3]=(_Float16)xc0.w;
            bhx[4]=(_Float16)xc1.x; bhx[5]=(_Float16)xc1.y; bhx[6]=(_Float16)xc1.z; bhx[7]=(_Float16)xc1.w;

            float4v acc[4];
            #pragma unroll
            for (int l = 0; l < 4; ++l)
                acc[l] = __builtin_amdgcn_mfma_f32_16x16x32_f16(ah[l][0], bhx, biasv[l], 0, 0, 0);
            #pragma unroll
            for (int kt = 1; kt < 3; ++kt) {
                half8 bh = *(const half8*)&SB[hidx(pr, n16, (kt - 1) * 32 + q * 8)];
                #pragma unroll
                for (int l = 0; l < 4; ++l)
                    acc[l] = __builtin_amdgcn_mfma_f32_16x16x32_f16(ah[l][kt], bh, acc[l], 0, 0, 0);
            }
            half4v hh;
            cell_update(acc, cs, hh, nullptr);
            *(half4v*)&SB[hidx(pw, n16, j0)] = hh;                 // LDS for own recurrence
            *(half4v*)(hstream + (size_t)t * H0T) = hh;            // global stream for L1

            if ((t & (CH - 1)) == (CH - 1)) {
                __syncthreads();   // drains vmcnt(0): all waves' h0 stores complete
                if (tid == 0)
                    __hip_atomic_store(prog + slice, (unsigned)(t / CH + 1),
                                       __ATOMIC_RELEASE, __HIP_MEMORY_SCOPE_AGENT);
            } else {
                BARRIER();         // LDS-only ordering; stores/loads ride across
            }
        }
        return;   // producer blocks exit; consumer writes out
    }

    // ======================= consumer: layer 1 + head =======================
    const _Float16* gbase = h0g + (size_t)slice * H0S + n16 * HCELLS;
    const int ka = q * 8, kb = 32 + q * 8;

    half8 a_cur, b_cur;
    for (int c = 0; c < NCH; ++c) {
        if (tid == 0) {
            unsigned v;
            while ((v = __hip_atomic_load(prog + slice, __ATOMIC_ACQUIRE,
                                          __HIP_MEMORY_SCOPE_AGENT)) < (unsigned)(c + 1))
                __builtin_amdgcn_s_sleep(8);
        }
        __syncthreads();   // all waves' loads below are ordered after the acquire+inv

        {
            const _Float16* p0 = gbase + (size_t)(c * CH) * H0T;
            a_cur = *(const half8*)(p0 + ka);
            b_cur = *(const half8*)(p0 + kb);
        }

        for (int i = 0; i < CH; ++i) {
            const int t = c * CH + i;

            half8 a_nxt, b_nxt;
            if (i + 1 < CH) {   // never prefetch past the published chunk
                const _Float16* pn = gbase + (size_t)(t + 1) * H0T;
                a_nxt = *(const half8*)(pn + ka);
                b_nxt = *(const half8*)(pn + kb);
            }

            const int sr = (t + 1) & 1;   // slot holding h1(t-1)
            const int sw = t & 1;

            float4v acc[4];
            #pragma unroll
            for (int l = 0; l < 4; ++l)
                acc[l] = __builtin_amdgcn_mfma_f32_16x16x32_f16(ah[l][0], a_cur, biasv[l], 0, 0, 0);
            #pragma unroll
            for (int l = 0; l < 4; ++l)
                acc[l] = __builtin_amdgcn_mfma_f32_16x16x32_f16(ah[l][1], b_cur, acc[l], 0, 0, 0);
            half8 c1 = *(const half8*)&SB[hidx(sr, n16, q * 8)];
            half8 c2 = *(const half8*)&SB[hidx(sr, n16, 32 + q * 8)];
            #pragma unroll
            for (int l = 0; l < 4; ++l)
                acc[l] = __builtin_amdgcn_mfma_f32_16x16x32_f16(ah[l][2], c1, acc[l], 0, 0, 0);
            #pragma unroll
            for (int l = 0; l < 4; ++l)
                acc[l] = __builtin_amdgcn_mfma_f32_16x16x32_f16(ah[l][3], c2, acc[l], 0, 0, 0);

            half4v hh;
            cell_update(acc, cs, hh, hlast);
            *(half4v*)&SB[hidx(sw, n16, j0)] = hh;
            BARRIER();

            a_cur = a_nxt; b_cur = b_nxt;
        }
    }

    // ---------------- head: relu(h1 @ W1^T + b1) @ W2^T + b2 ----------------
    float* h1f = HS;             // [16][68]
    float* hid = HS + 16 * 68;   // [16][33]
    *(float4*)&h1f[n16 * 68 + j0] = *(const float4*)hlast;
    __syncthreads();

    {
        const int n2 = tid >> 4, m = tid & 15;
        float s0 = b1[m], s1 = b1[m + 16];
        const float* w0p = W1 + m * HCELLS;
        const float* w1p = W1 + (m + 16) * HCELLS;
        #pragma unroll
        for (int j = 0; j < HCELLS; ++j) {
            float hv = h1f[n2 * 68 + j];
            s0 = fmaf(w0p[j], hv, s0);
            s1 = fmaf(w1p[j], hv, s1);
        }
        hid[n2 * 33 + m]      = fmaxf(s0, 0.0f);
        hid[n2 * 33 + m + 16] = fmaxf(s1, 0.0f);
    }
    __syncthreads();

    if (tid < NB) {
        float s = b2[0];
        #pragma unroll
        for (int m = 0; m < 32; ++m) s = fmaf(W2[m], hid[tid * 33 + m], s);
        out[b0 + tid] = s;
    }
}

// ======================= fallback: verified round-2 single-grid kernel =======================
#define TBF     512
#define FB_H0   0
#define FB_H1   (2*16*STRH)
#define FB_HALFS (FB_H1 + 2*16*STRH)

__global__ void __launch_bounds__(TBF, 2)
lstm2_mfma_fallback(const float* __restrict__ x,
                    const float* __restrict__ Wih0, const float* __restrict__ Whh0,
                    const float* __restrict__ bih0, const float* __restrict__ bhh0,
                    const float* __restrict__ Wih1, const float* __restrict__ Whh1,
                    const float* __restrict__ bih1, const float* __restrict__ bhh1,
                    const float* __restrict__ W1,   const float* __restrict__ b1,
                    const float* __restrict__ W2,   const float* __restrict__ b2,
                    float* __restrict__ out)
{
    const int tid  = threadIdx.x;
    const int wid  = tid >> 6;
    const int grp  = wid >> 2;
    const int wl   = wid & 3;
    const int lane = tid & 63;
    const int n16  = lane & 15;
    const int q    = lane >> 4;
    const int j0   = wl * 16 + q * 4;
    const int b0   = blockIdx.x * NB;

    __shared__ __align__(16) _Float16 SB[FB_HALFS];
    __shared__ __align__(16) float HS[16 * 68 + 16 * 33];

    const float gsc[4] = {-LOG2E, -LOG2E, SLOG2E, -LOG2E};
    half8 ah[4][4];
    float4v biasv[4];

    #pragma unroll
    for (int l = 0; l < 4; ++l) {
        const int row = (l * 4 + wl) * 16 + n16;
        const float g = gsc[l];
        float v[8];
        if (grp == 0) {
            {
                const float4* p = (const float4*)(Wih0 + row * DIN + q * 8);
                float4 u0 = p[0], u1 = p[1];
                v[0]=g*u0.x; v[1]=g*u0.y; v[2]=g*u0.z; v[3]=g*u0.w;
                v[4]=g*u1.x; v[5]=g*u1.y; v[6]=g*u1.z; v[7]=g*u1.w;
                cvt8(v, ah[l][0]);
            }
            #pragma unroll
            for (int kt = 1; kt < 3; ++kt) {
                const float4* p = (const float4*)(Whh0 + row * HCELLS + (kt - 1) * 32 + q * 8);
                float4 u0 = p[0], u1 = p[1];
                v[0]=g*u0.x; v[1]=g*u0.y; v[2]=g*u0.z; v[3]=g*u0.w;
                v[4]=g*u1.x; v[5]=g*u1.y; v[6]=g*u1.z; v[7]=g*u1.w;
                cvt8(v, ah[l][kt]);
            }
            const int r0 = l * 64 + j0;
            float4v bi = *(const float4v*)(bih0 + r0);
            float4v bh = *(const float4v*)(bhh0 + r0);
            biasv[l] = (bi + bh) * g;
        } else {
            #pragma unroll
            for (int kt = 0; kt < 4; ++kt) {
                const float* base = (kt < 2) ? (Wih1 + row * HCELLS + kt * 32)
                                             : (Whh1 + row * HCELLS + (kt - 2) * 32);
                const float4* p = (const float4*)(base + q * 8);
                float4 u0 = p[0], u1 = p[1];
                v[0]=g*u0.x; v[1]=g*u0.y; v[2]=g*u0.z; v[3]=g*u0.w;
                v[4]=g*u1.x; v[5]=g*u1.y; v[6]=g*u1.z; v[7]=g*u1.w;
                cvt8(v, ah[l][kt]);
            }
            const int r0 = l * 64 + j0;
            float4v bi = *(const float4v*)(bih1 + r0);
            float4v bh = *(const float4v*)(bhh1 + r0);
            biasv[l] = (bi + bh) * g;
        }
    }

    for (int i = tid; i < FB_HALFS / 2; i += TBF) ((int*)SB)[i] = 0;

    const float* xq = nullptr;
    float4 xn0, xn1;
    if (grp == 0) {
        xq = x + ((size_t)(b0 + n16) * T) * DIN + q * 8;
        xn0 = *(const float4*)xq;
        xn1 = *(const float4*)(xq + 4);
        xq += DIN;
    }
    __syncthreads();

    float cs[4] = {0, 0, 0, 0};
    float hlast[4];

    #pragma unroll 2
    for (int t = 0; t < T; ++t) {
        const int pr = t & 1, pw = pr ^ 1;
        if (grp == 0) {
            float4 xc0 = xn0, xc1 = xn1;
            if (t + 1 < T) { xn0 = *(const float4*)xq; xn1 = *(const float4*)(xq + 4); xq += DIN; }
            half8 bhx;
            bhx[0]=(_Float16)xc0.x; bhx[1]=(_Float16)xc0.y; bhx[2]=(_Float16)xc0.z; bhx[3]=(_Float16)xc0.w;
            bhx[4]=(_Float16)xc1.x; bhx[5]=(_Float16)xc1.y; bhx[6]=(_Float16)xc1.z; bhx[7]=(_Float16)xc1.w;
            float4v acc[4];
            #pragma unroll
            for (int l = 0; l < 4; ++l)
                acc[l] = __builtin_amdgcn_mfma_f32_16x16x32_f16(ah[l][0], bhx, biasv[l], 0, 0, 0);
            #pragma unroll
            for (int kt = 1; kt < 3; ++kt) {
                half8 bh = *(const half8*)&SB[FB_H0 + hidx(pr, n16, (kt - 1) * 32 + q * 8)];
                #pragma unroll
                for (int l = 0; l < 4; ++l)
                    acc[l] = __builtin_amdgcn_mfma_f32_16x16x32_f16(ah[l][kt], bh, acc[l], 0, 0, 0);
            }
            half4v hh;
            cell_update(acc, cs, hh, nullptr);
            *(half4v*)&SB[FB_H0 + hidx(pw, n16, j0)] = hh;
        } else if (t > 0) {
            float4v acc[4];
            #pragma unroll
            for (int l = 0; l < 4; ++l) acc[l] = biasv[l];
            #pragma unroll
            for (int kt = 0; kt < 4; ++kt) {
                half8 bh = (kt < 2)
                    ? *(const half8*)&SB[FB_H0 + hidx(pr, n16, kt * 32 + q * 8)]
                    : *(const half8*)&SB[FB_H1 + hidx(pw, n16, (kt - 2) * 32 + q * 8)];
                #pragma unroll
                for (int l = 0; l < 4; ++l)
                    acc[l] = __builtin_amdgcn_mfma_f32_16x16x32_f16(ah[l][kt], bh, acc[l], 0, 0, 0);
            }
            half4v hh;
            cell_update(acc, cs, hh, nullptr);
            *(half4v*)&SB[FB_H1 + hidx(pr, n16, j0)] = hh;
        }
        BARRIER();
    }

    float* h1f = HS;
    float* hid = HS + 16 * 68;
    if (grp == 1) {
        float4v acc[4];
        #pragma unroll
        for (int l = 0; l < 4; ++l) acc[l] = biasv[l];
        #pragma unroll
        for (int kt = 0; kt < 4; ++kt) {
            half8 bh = (kt < 2)
                ? *(const half8*)&SB[FB_H0 + hidx(0, n16, kt * 32 + q * 8)]
                : *(const half8*)&SB[FB_H1 + hidx(1, n16, (kt - 2) * 32 + q * 8)];
            #pragma unroll
            for (int l = 0; l < 4; ++l)
                acc[l] = __builtin_amdgcn_mfma_f32_16x16x32_f16(ah[l][kt], bh, acc[l], 0, 0, 0);
        }
        half4v hh;
        cell_update(acc, cs, hh, hlast);
        *(float4*)&h1f[n16 * 68 + j0] = *(const float4*)hlast;
    }
    __syncthreads();

    if (tid < 256) {
        const int n2 = tid >> 4, m = tid & 15;
        float s0 = b1[m], s1 = b1[m + 16];
        const float* w0p = W1 + m * HCELLS;
        const float* w1p = W1 + (m + 16) * HCELLS;
        #pragma unroll
        for (int j = 0; j < HCELLS; ++j) {
            float hv = h1f[n2 * 68 + j];
            s0 = fmaf(w0p[j], hv, s0);
            s1 = fmaf(w1p[j], hv, s1);
        }
        hid[n2 * 33 + m]      = fmaxf(s0, 0.0f);
        hid[n2 * 33 + m + 16] = fmaxf(s1, 0.0f);
    }
    __syncthreads();

    if (tid < NB) {
        float s = b2[0];
        #pragma unroll
        for (int m = 0; m < 32; ++m) s = fmaf(W2[m], hid[tid * 33 + m], s);
        out[b0 + tid] = s;
    }
}

extern "C" void kernel_launch(void* const* d_in, const int* in_sizes, int n_in,
                              void* d_out, int out_size, void* d_ws, size_t ws_size,
                              hipStream_t stream) {
    const float* x    = (const float*)d_in[0];
    const float* Wih0 = (const float*)d_in[1];
    const float* Whh0 = (const float*)d_in[2];
    const float* bih0 = (const float*)d_in[3];
    const float* bhh0 = (const float*)d_in[4];
    const float* Wih1 = (const float*)d_in[5];
    const float* Whh1 = (const float*)d_in[6];
    const float* bih1 = (const float*)d_in[7];
    const float* bhh1 = (const float*)d_in[8];
    const float* W1   = (const float*)d_in[9];
    const float* b1   = (const float*)d_in[10];
    const float* W2   = (const float*)d_in[11];
    const float* b2   = (const float*)d_in[12];
    float* out = (float*)d_out;

    if (d_ws != nullptr && ws_size >= WS_NEED) {
        hipMemsetAsync(d_ws, 0, WS_FLAG_BYTES, stream);   // reset progress flags each launch
        unsigned*  prog = (unsigned*)d_ws;
        _Float16*  h0g  = (_Float16*)((char*)d_ws + WS_FLAG_BYTES);
        hipLaunchKernelGGL(lstm2_pipe_kernel, dim3(2 * NSLICE), dim3(TB), 0, stream,
                           x, Wih0, Whh0, bih0, bhh0, Wih1, Whh1, bih1, bhh1,
                           W1, b1, W2, b2, prog, h0g, out);
    } else {
        hipLaunchKernelGGL(lstm2_mfma_fallback, dim3(NSLICE), dim3(TBF), 0, stream,
                           x, Wih0, Whh0, bih0, bhh0, Wih1, Whh1, bih1, bhh1,
                           W1, b1, W2, b2, out);
    }
}

// Round 4
// 446.823 us; speedup vs baseline: 1.0313x; 1.0313x over previous
//
#include <hip/hip_runtime.h>

#define T       512
#define DIN     32
#define HCELLS  64
#define NB      16      // batch elems per block (MFMA N dim)
#define NSLICE  64      // 1024 / NB
#define TB      256     // pipeline kernel: 4 waves (one layer per block)
#define CH      16      // chunk steps per cross-block handoff
#define NCH     (T / CH)

typedef _Float16 half8  __attribute__((ext_vector_type(8)));
typedef _Float16 half4v __attribute__((ext_vector_type(4)));
typedef float    float4v __attribute__((ext_vector_type(4)));

#define STRH    72      // h rows: 64 + 8 pad (halfs)
#define SB_HALFS (2*16*STRH)        // one layer's double-buffered h state

#define LOG2E   1.44269504f
#define SLOG2E  2.88539008f     // 2*log2(e); cell state kept as cs = SLOG2E * c

// Raw barrier: orders LDS but leaves global loads/stores in flight.
#define BARRIER() asm volatile("s_waitcnt lgkmcnt(0)\n\ts_barrier" ::: "memory")

// workspace layout
#define WS_FLAG_BYTES 4096
#define H0T   (16 * HCELLS)                  // halfs per step per slice
#define H0S   ((size_t)T * H0T)              // halfs per slice
#define WS_NEED (WS_FLAG_BYTES + (size_t)NSLICE * H0S * sizeof(_Float16))

__device__ __forceinline__ int hidx(int p, int n, int k) { return (p * 16 + n) * STRH + k; }

__device__ __forceinline__ void cvt8(const float* v, half8& hi) {
    #pragma unroll
    for (int e = 0; e < 8; ++e) hi[e] = (_Float16)v[e];
}

// Scaled-domain LSTM cell update, stage-major (SoA) over the 4 rows so the
// 4 independent chains interleave: all exp2s batched, then VALU stages, then
// rcps.  Per-element arithmetic identical to the verified row-major version.
__device__ __forceinline__ void cell_vec(float4v z0, float4v z1, float4v z2, float4v z3,
                                         float4v& cs, half4v& hh, float4v* hout)
{
    float4v ei, ef, G2, eo, rFP, C2, rOC;
    #pragma unroll
    for (int r = 0; r < 4; ++r) ei[r] = __builtin_amdgcn_exp2f(z0[r]);   // e^{-zi}
    #pragma unroll
    for (int r = 0; r < 4; ++r) ef[r] = __builtin_amdgcn_exp2f(z1[r]);   // e^{-zf}
    #pragma unroll
    for (int r = 0; r < 4; ++r) G2[r] = __builtin_amdgcn_exp2f(z2[r]);   // e^{2 zg}
    #pragma unroll
    for (int r = 0; r < 4; ++r) eo[r] = __builtin_amdgcn_exp2f(z3[r]);   // e^{-zo}

    float4v I  = 1.0f + ei;
    float4v F  = 1.0f + ef;
    float4v Gp = 1.0f + G2;
    float4v P  = I * Gp;
    float4v FP = F * P;
    #pragma unroll
    for (int r = 0; r < 4; ++r) rFP[r] = __builtin_amdgcn_rcpf(FP[r]);

    float4v Gms, num, csn;
    #pragma unroll
    for (int r = 0; r < 4; ++r) Gms[r] = fmaf(SLOG2E, G2[r], -SLOG2E);
    #pragma unroll
    for (int r = 0; r < 4; ++r) num[r] = fmaf(F[r], Gms[r], cs[r] * P[r]);
    csn = num * rFP;
    #pragma unroll
    for (int r = 0; r < 4; ++r) csn[r] = fminf(fmaxf(csn[r], -50.0f), 50.0f);
    cs = csn;

    #pragma unroll
    for (int r = 0; r < 4; ++r) C2[r] = __builtin_amdgcn_exp2f(csn[r]);
    float4v O   = 1.0f + eo;
    float4v OCp = O * (1.0f + C2);
    #pragma unroll
    for (int r = 0; r < 4; ++r) rOC[r] = __builtin_amdgcn_rcpf(OCp[r]);
    float4v h = (C2 - 1.0f) * rOC;
    if (hout) *hout = h;
    #pragma unroll
    for (int r = 0; r < 4; ++r) hh[r] = (_Float16)h[r];
}

// ======================= pipelined 2-stage kernel (128 blocks) =======================
// block g: role = (g>>3)&1 (0=L0 producer, 1=L1 consumer), slice = ((g>>4)<<3)|(g&7).
// Pair (g, g+8) shares a slice and (under blockid%8 XCD round-robin) an XCD L2.
__global__ void __launch_bounds__(TB, 1)
lstm2_pipe_kernel(const float* __restrict__ x,
                  const float* __restrict__ Wih0, const float* __restrict__ Whh0,
                  const float* __restrict__ bih0, const float* __restrict__ bhh0,
                  const float* __restrict__ Wih1, const float* __restrict__ Whh1,
                  const float* __restrict__ bih1, const float* __restrict__ bhh1,
                  const float* __restrict__ W1,   const float* __restrict__ b1,
                  const float* __restrict__ W2,   const float* __restrict__ b2,
                  unsigned* __restrict__ prog, _Float16* __restrict__ h0g,
                  float* __restrict__ out)
{
    const int tid  = threadIdx.x;
    const int wl   = tid >> 6;          // wave 0..3: hidden slice wl*16..wl*16+15
    const int lane = tid & 63;
    const int n16  = lane & 15;         // MFMA free index / local batch
    const int q    = lane >> 4;         // quad 0..3
    const int j0   = wl * 16 + q * 4;   // hidden-unit base (4 rows)

    const int g     = blockIdx.x;
    const int role  = (g >> 3) & 1;
    const int slice = ((g >> 4) << 3) | (g & 7);
    const int b0    = slice * NB;

    __shared__ __align__(16) _Float16 SB[SB_HALFS];
    __shared__ __align__(16) float HS[16 * 68 + 16 * 33];

    const float gsc[4] = {-LOG2E, -LOG2E, SLOG2E, -LOG2E};

    // ---------------- per-role weight fragments (single fp16) ----------------
    half8 ah[4][4];
    float4v biasv[4];

    #pragma unroll
    for (int l = 0; l < 4; ++l) {
        const int row = (l * 4 + wl) * 16 + n16;
        const float g2 = gsc[l];
        float v[8];
        if (role == 0) {
            {
                const float4* p = (const float4*)(Wih0 + row * DIN + q * 8);
                float4 u0 = p[0], u1 = p[1];
                v[0]=g2*u0.x; v[1]=g2*u0.y; v[2]=g2*u0.z; v[3]=g2*u0.w;
                v[4]=g2*u1.x; v[5]=g2*u1.y; v[6]=g2*u1.z; v[7]=g2*u1.w;
                cvt8(v, ah[l][0]);
            }
            #pragma unroll
            for (int kt = 1; kt < 3; ++kt) {
                const float4* p = (const float4*)(Whh0 + row * HCELLS + (kt - 1) * 32 + q * 8);
                float4 u0 = p[0], u1 = p[1];
                v[0]=g2*u0.x; v[1]=g2*u0.y; v[2]=g2*u0.z; v[3]=g2*u0.w;
                v[4]=g2*u1.x; v[5]=g2*u1.y; v[6]=g2*u1.z; v[7]=g2*u1.w;
                cvt8(v, ah[l][kt]);
            }
            const int r0 = l * 64 + j0;
            float4v bi = *(const float4v*)(bih0 + r0);
            float4v bh = *(const float4v*)(bhh0 + r0);
            biasv[l] = (bi + bh) * g2;
        } else {
            #pragma unroll
            for (int kt = 0; kt < 4; ++kt) {
                const float* base = (kt < 2) ? (Wih1 + row * HCELLS + kt * 32)
                                             : (Whh1 + row * HCELLS + (kt - 2) * 32);
                const float4* p = (const float4*)(base + q * 8);
                float4 u0 = p[0], u1 = p[1];
                v[0]=g2*u0.x; v[1]=g2*u0.y; v[2]=g2*u0.z; v[3]=g2*u0.w;
                v[4]=g2*u1.x; v[5]=g2*u1.y; v[6]=g2*u1.z; v[7]=g2*u1.w;
                cvt8(v, ah[l][kt]);
            }
            const int r0 = l * 64 + j0;
            float4v bi = *(const float4v*)(bih1 + r0);
            float4v bh = *(const float4v*)(bhh1 + r0);
            biasv[l] = (bi + bh) * g2;
        }
    }

    // zero the h double-buffer (h(-1) = 0)
    for (int i = tid; i < SB_HALFS / 2; i += TB) ((int*)SB)[i] = 0;
    __syncthreads();

    float4v cs4 = {0.f, 0.f, 0.f, 0.f};
    float4v hl4;

    if (role == 0) {
        // ======================= producer: layer 0 =======================
        const float* xq = x + ((size_t)(b0 + n16) * T) * DIN + q * 8;
        float4 xn0 = ((const float4*)xq)[0];
        float4 xn1 = ((const float4*)xq)[1];
        xq += DIN;

        _Float16* hstream = h0g + (size_t)slice * H0S + n16 * HCELLS + j0;

        #pragma unroll 2
        for (int t = 0; t < T; ++t) {
            const int pr = t & 1, pw = pr ^ 1;

            // x(t) from regs; prefetch x(t+1) (rides across the raw barrier)
            float4 xc0 = xn0, xc1 = xn1;
            if (t + 1 < T) { xn0 = ((const float4*)xq)[0]; xn1 = ((const float4*)xq)[1]; xq += DIN; }

            half8 bhx;
            bhx[0]=(_Float16)xc0.x; bhx[1]=(_Float16)xc0.y; bhx[2]=(_Float16)xc0.z; bhx[3]=(_Float16)xc0.w;
            bhx[4]=(_Float16)xc1.x; bhx[5]=(_Float16)xc1.y; bhx[6]=(_Float16)xc1.z; bhx[7]=(_Float16)xc1.w;

            // bias + x-part first (no LDS dependence), then depth-2 LDS MFMA chain
            float4v acc[4];
            #pragma unroll
            for (int l = 0; l < 4; ++l)
                acc[l] = __builtin_amdgcn_mfma_f32_16x16x32_f16(ah[l][0], bhx, biasv[l], 0, 0, 0);
            half8 bh0a = *(const half8*)&SB[hidx(pr, n16, q * 8)];
            half8 bh0b = *(const half8*)&SB[hidx(pr, n16, 32 + q * 8)];
            #pragma unroll
            for (int l = 0; l < 4; ++l)
                acc[l] = __builtin_amdgcn_mfma_f32_16x16x32_f16(ah[l][1], bh0a, acc[l], 0, 0, 0);
            #pragma unroll
            for (int l = 0; l < 4; ++l)
                acc[l] = __builtin_amdgcn_mfma_f32_16x16x32_f16(ah[l][2], bh0b, acc[l], 0, 0, 0);

            half4v hh;
            cell_vec(acc[0], acc[1], acc[2], acc[3], cs4, hh, nullptr);
            *(half4v*)&SB[hidx(pw, n16, j0)] = hh;                 // LDS for own recurrence
            *(half4v*)(hstream + (size_t)t * H0T) = hh;            // global stream for L1

            if ((t & (CH - 1)) == (CH - 1)) {
                __syncthreads();   // drains vmcnt(0): all waves' h0 stores complete
                if (tid == 0)
                    __hip_atomic_store(prog + slice, (unsigned)(t / CH + 1),
                                       __ATOMIC_RELEASE, __HIP_MEMORY_SCOPE_AGENT);
            } else {
                BARRIER();         // LDS-only ordering; stores/loads ride across
            }
        }
        return;   // producer blocks exit; consumer writes out
    }

    // ======================= consumer: layer 1 + head =======================
    const _Float16* gbase = h0g + (size_t)slice * H0S + n16 * HCELLS;
    const int ka = q * 8, kb = 32 + q * 8;

    half8 a_cur, b_cur;
    for (int c = 0; c < NCH; ++c) {
        if (tid == 0) {
            unsigned v;
            while ((v = __hip_atomic_load(prog + slice, __ATOMIC_ACQUIRE,
                                          __HIP_MEMORY_SCOPE_AGENT)) < (unsigned)(c + 1))
                __builtin_amdgcn_s_sleep(2);
        }
        __syncthreads();   // all waves' loads below are ordered after the acquire+inv

        {
            const _Float16* p0 = gbase + (size_t)(c * CH) * H0T;
            a_cur = *(const half8*)(p0 + ka);
            b_cur = *(const half8*)(p0 + kb);
        }

        #pragma unroll 2
        for (int i = 0; i < CH; ++i) {
            const int t = c * CH + i;
            const int sr = (i + 1) & 1;   // slot holding h1(t-1)   (CH even => t&1 == i&1)
            const int sw = i & 1;

            half8 a_nxt, b_nxt;
            if (i + 1 < CH) {   // never prefetch past the published chunk
                const _Float16* pn = gbase + (size_t)(t + 1) * H0T;
                a_nxt = *(const half8*)(pn + ka);
                b_nxt = *(const half8*)(pn + kb);
            }

            // bias + global-h0 part first (no LDS dependence this region),
            // then depth-2 LDS MFMA chain on h1(t-1)
            float4v acc[4];
            #pragma unroll
            for (int l = 0; l < 4; ++l)
                acc[l] = __builtin_amdgcn_mfma_f32_16x16x32_f16(ah[l][0], a_cur, biasv[l], 0, 0, 0);
            #pragma unroll
            for (int l = 0; l < 4; ++l)
                acc[l] = __builtin_amdgcn_mfma_f32_16x16x32_f16(ah[l][1], b_cur, acc[l], 0, 0, 0);
            half8 c1 = *(const half8*)&SB[hidx(sr, n16, q * 8)];
            half8 c2 = *(const half8*)&SB[hidx(sr, n16, 32 + q * 8)];
            #pragma unroll
            for (int l = 0; l < 4; ++l)
                acc[l] = __builtin_amdgcn_mfma_f32_16x16x32_f16(ah[l][2], c1, acc[l], 0, 0, 0);
            #pragma unroll
            for (int l = 0; l < 4; ++l)
                acc[l] = __builtin_amdgcn_mfma_f32_16x16x32_f16(ah[l][3], c2, acc[l], 0, 0, 0);

            half4v hh;
            cell_vec(acc[0], acc[1], acc[2], acc[3], cs4, hh, &hl4);
            *(half4v*)&SB[hidx(sw, n16, j0)] = hh;
            BARRIER();

            a_cur = a_nxt; b_cur = b_nxt;
        }
    }

    // ---------------- head: relu(h1 @ W1^T + b1) @ W2^T + b2 ----------------
    float* h1f = HS;             // [16][68]
    float* hid = HS + 16 * 68;   // [16][33]
    *(float4v*)&h1f[n16 * 68 + j0] = hl4;
    __syncthreads();

    {
        const int n2 = tid >> 4, m = tid & 15;
        float s0 = b1[m], s1 = b1[m + 16];
        const float* w0p = W1 + m * HCELLS;
        const float* w1p = W1 + (m + 16) * HCELLS;
        #pragma unroll
        for (int j = 0; j < HCELLS; ++j) {
            float hv = h1f[n2 * 68 + j];
            s0 = fmaf(w0p[j], hv, s0);
            s1 = fmaf(w1p[j], hv, s1);
        }
        hid[n2 * 33 + m]      = fmaxf(s0, 0.0f);
        hid[n2 * 33 + m + 16] = fmaxf(s1, 0.0f);
    }
    __syncthreads();

    if (tid < NB) {
        float s = b2[0];
        #pragma unroll
        for (int m = 0; m < 32; ++m) s = fmaf(W2[m], hid[tid * 33 + m], s);
        out[b0 + tid] = s;
    }
}

// ======================= fallback: verified round-2 single-grid kernel =======================
#define TBF     512
#define FB_H0   0
#define FB_H1   (2*16*STRH)
#define FB_HALFS (FB_H1 + 2*16*STRH)

__device__ __forceinline__ void cell_update(const float4v acc[4], float* cs,
                                            half4v& hh, float* hout)
{
    #pragma unroll
    for (int r = 0; r < 4; ++r) {
        float ei = __builtin_amdgcn_exp2f(acc[0][r]);
        float ef = __builtin_amdgcn_exp2f(acc[1][r]);
        float G2 = __builtin_amdgcn_exp2f(acc[2][r]);
        float I  = 1.0f + ei, F = 1.0f + ef;
        float Gp = 1.0f + G2;
        float Gms = fmaf(SLOG2E, G2, -SLOG2E);
        float P   = I * Gp;
        float num = fmaf(F, Gms, cs[r] * P);
        float csn = num * __builtin_amdgcn_rcpf(F * P);
        csn = fminf(fmaxf(csn, -50.0f), 50.0f);
        cs[r] = csn;
        float eo = __builtin_amdgcn_exp2f(acc[3][r]);
        float C2 = __builtin_amdgcn_exp2f(csn);
        float O  = 1.0f + eo;
        float Cp = 1.0f + C2, Cm = C2 - 1.0f;
        float h  = Cm * __builtin_amdgcn_rcpf(O * Cp);
        if (hout) hout[r] = h;
        hh[r] = (_Float16)h;
    }
}

__global__ void __launch_bounds__(TBF, 2)
lstm2_mfma_fallback(const float* __restrict__ x,
                    const float* __restrict__ Wih0, const float* __restrict__ Whh0,
                    const float* __restrict__ bih0, const float* __restrict__ bhh0,
                    const float* __restrict__ Wih1, const float* __restrict__ Whh1,
                    const float* __restrict__ bih1, const float* __restrict__ bhh1,
                    const float* __restrict__ W1,   const float* __restrict__ b1,
                    const float* __restrict__ W2,   const float* __restrict__ b2,
                    float* __restrict__ out)
{
    const int tid  = threadIdx.x;
    const int wid  = tid >> 6;
    const int grp  = wid >> 2;
    const int wl   = wid & 3;
    const int lane = tid & 63;
    const int n16  = lane & 15;
    const int q    = lane >> 4;
    const int j0   = wl * 16 + q * 4;
    const int b0   = blockIdx.x * NB;

    __shared__ __align__(16) _Float16 SB[FB_HALFS];
    __shared__ __align__(16) float HS[16 * 68 + 16 * 33];

    const float gsc[4] = {-LOG2E, -LOG2E, SLOG2E, -LOG2E};
    half8 ah[4][4];
    float4v biasv[4];

    #pragma unroll
    for (int l = 0; l < 4; ++l) {
        const int row = (l * 4 + wl) * 16 + n16;
        const float g = gsc[l];
        float v[8];
        if (grp == 0) {
            {
                const float4* p = (const float4*)(Wih0 + row * DIN + q * 8);
                float4 u0 = p[0], u1 = p[1];
                v[0]=g*u0.x; v[1]=g*u0.y; v[2]=g*u0.z; v[3]=g*u0.w;
                v[4]=g*u1.x; v[5]=g*u1.y; v[6]=g*u1.z; v[7]=g*u1.w;
                cvt8(v, ah[l][0]);
            }
            #pragma unroll
            for (int kt = 1; kt < 3; ++kt) {
                const float4* p = (const float4*)(Whh0 + row * HCELLS + (kt - 1) * 32 + q * 8);
                float4 u0 = p[0], u1 = p[1];
                v[0]=g*u0.x; v[1]=g*u0.y; v[2]=g*u0.z; v[3]=g*u0.w;
                v[4]=g*u1.x; v[5]=g*u1.y; v[6]=g*u1.z; v[7]=g*u1.w;
                cvt8(v, ah[l][kt]);
            }
            const int r0 = l * 64 + j0;
            float4v bi = *(const float4v*)(bih0 + r0);
            float4v bh = *(const float4v*)(bhh0 + r0);
            biasv[l] = (bi + bh) * g;
        } else {
            #pragma unroll
            for (int kt = 0; kt < 4; ++kt) {
                const float* base = (kt < 2) ? (Wih1 + row * HCELLS + kt * 32)
                                             : (Whh1 + row * HCELLS + (kt - 2) * 32);
                const float4* p = (const float4*)(base + q * 8);
                float4 u0 = p[0], u1 = p[1];
                v[0]=g*u0.x; v[1]=g*u0.y; v[2]=g*u0.z; v[3]=g*u0.w;
                v[4]=g*u1.x; v[5]=g*u1.y; v[6]=g*u1.z; v[7]=g*u1.w;
                cvt8(v, ah[l][kt]);
            }
            const int r0 = l * 64 + j0;
            float4v bi = *(const float4v*)(bih1 + r0);
            float4v bh = *(const float4v*)(bhh1 + r0);
            biasv[l] = (bi + bh) * g;
        }
    }

    for (int i = tid; i < FB_HALFS / 2; i += TBF) ((int*)SB)[i] = 0;

    const float* xq = nullptr;
    float4 xn0, xn1;
    if (grp == 0) {
        xq = x + ((size_t)(b0 + n16) * T) * DIN + q * 8;
        xn0 = *(const float4*)xq;
        xn1 = *(const float4*)(xq + 4);
        xq += DIN;
    }
    __syncthreads();

    float cs[4] = {0, 0, 0, 0};
    float hlast[4];

    #pragma unroll 2
    for (int t = 0; t < T; ++t) {
        const int pr = t & 1, pw = pr ^ 1;
        if (grp == 0) {
            float4 xc0 = xn0, xc1 = xn1;
            if (t + 1 < T) { xn0 = *(const float4*)xq; xn1 = *(const float4*)(xq + 4); xq += DIN; }
            half8 bhx;
            bhx[0]=(_Float16)xc0.x; bhx[1]=(_Float16)xc0.y; bhx[2]=(_Float16)xc0.z; bhx[3]=(_Float16)xc0.w;
            bhx[4]=(_Float16)xc1.x; bhx[5]=(_Float16)xc1.y; bhx[6]=(_Float16)xc1.z; bhx[7]=(_Float16)xc1.w;
            float4v acc[4];
            #pragma unroll
            for (int l = 0; l < 4; ++l)
                acc[l] = __builtin_amdgcn_mfma_f32_16x16x32_f16(ah[l][0], bhx, biasv[l], 0, 0, 0);
            #pragma unroll
            for (int kt = 1; kt < 3; ++kt) {
                half8 bh = *(const half8*)&SB[FB_H0 + hidx(pr, n16, (kt - 1) * 32 + q * 8)];
                #pragma unroll
                for (int l = 0; l < 4; ++l)
                    acc[l] = __builtin_amdgcn_mfma_f32_16x16x32_f16(ah[l][kt], bh, acc[l], 0, 0, 0);
            }
            half4v hh;
            cell_update(acc, cs, hh, nullptr);
            *(half4v*)&SB[FB_H0 + hidx(pw, n16, j0)] = hh;
        } else if (t > 0) {
            float4v acc[4];
            #pragma unroll
            for (int l = 0; l < 4; ++l) acc[l] = biasv[l];
            #pragma unroll
            for (int kt = 0; kt < 4; ++kt) {
                half8 bh = (kt < 2)
                    ? *(const half8*)&SB[FB_H0 + hidx(pr, n16, kt * 32 + q * 8)]
                    : *(const half8*)&SB[FB_H1 + hidx(pw, n16, (kt - 2) * 32 + q * 8)];
                #pragma unroll
                for (int l = 0; l < 4; ++l)
                    acc[l] = __builtin_amdgcn_mfma_f32_16x16x32_f16(ah[l][kt], bh, acc[l], 0, 0, 0);
            }
            half4v hh;
            cell_update(acc, cs, hh, nullptr);
            *(half4v*)&SB[FB_H1 + hidx(pr, n16, j0)] = hh;
        }
        BARRIER();
    }

    float* h1f = HS;
    float* hid = HS + 16 * 68;
    if (grp == 1) {
        float4v acc[4];
        #pragma unroll
        for (int l = 0; l < 4; ++l) acc[l] = biasv[l];
        #pragma unroll
        for (int kt = 0; kt < 4; ++kt) {
            half8 bh = (kt < 2)
                ? *(const half8*)&SB[FB_H0 + hidx(0, n16, kt * 32 + q * 8)]
                : *(const half8*)&SB[FB_H1 + hidx(1, n16, (kt - 2) * 32 + q * 8)];
            #pragma unroll
            for (int l = 0; l < 4; ++l)
                acc[l] = __builtin_amdgcn_mfma_f32_16x16x32_f16(ah[l][kt], bh, acc[l], 0, 0, 0);
        }
        half4v hh;
        cell_update(acc, cs, hh, hlast);
        *(float4*)&h1f[n16 * 68 + j0] = *(const float4*)hlast;
    }
    __syncthreads();

    if (tid < 256) {
        const int n2 = tid >> 4, m = tid & 15;
        float s0 = b1[m], s1 = b1[m + 16];
        const float* w0p = W1 + m * HCELLS;
        const float* w1p = W1 + (m + 16) * HCELLS;
        #pragma unroll
        for (int j = 0; j < HCELLS; ++j) {
            float hv = h1f[n2 * 68 + j];
            s0 = fmaf(w0p[j], hv, s0);
            s1 = fmaf(w1p[j], hv, s1);
        }
        hid[n2 * 33 + m]      = fmaxf(s0, 0.0f);
        hid[n2 * 33 + m + 16] = fmaxf(s1, 0.0f);
    }
    __syncthreads();

    if (tid < NB) {
        float s = b2[0];
        #pragma unroll
        for (int m = 0; m < 32; ++m) s = fmaf(W2[m], hid[tid * 33 + m], s);
        out[b0 + tid] = s;
    }
}

extern "C" void kernel_launch(void* const* d_in, const int* in_sizes, int n_in,
                              void* d_out, int out_size, void* d_ws, size_t ws_size,
                              hipStream_t stream) {
    const float* x    = (const float*)d_in[0];
    const float* Wih0 = (const float*)d_in[1];
    const float* Whh0 = (const float*)d_in[2];
    const float* bih0 = (const float*)d_in[3];
    const float* bhh0 = (const float*)d_in[4];
    const float* Wih1 = (const float*)d_in[5];
    const float* Whh1 = (const float*)d_in[6];
    const float* bih1 = (const float*)d_in[7];
    const float* bhh1 = (const float*)d_in[8];
    const float* W1   = (const float*)d_in[9];
    const float* b1   = (const float*)d_in[10];
    const float* W2   = (const float*)d_in[11];
    const float* b2   = (const float*)d_in[12];
    float* out = (float*)d_out;

    if (d_ws != nullptr && ws_size >= WS_NEED) {
        hipMemsetAsync(d_ws, 0, WS_FLAG_BYTES, stream);   // reset progress flags each launch
        unsigned*  prog = (unsigned*)d_ws;
        _Float16*  h0g  = (_Float16*)((char*)d_ws + WS_FLAG_BYTES);
        hipLaunchKernelGGL(lstm2_pipe_kernel, dim3(2 * NSLICE), dim3(TB), 0, stream,
                           x, Wih0, Whh0, bih0, bhh0, Wih1, Whh1, bih1, bhh1,
                           W1, b1, W2, b2, prog, h0g, out);
    } else {
        hipLaunchKernelGGL(lstm2_mfma_fallback, dim3(NSLICE), dim3(TBF), 0, stream,
                           x, Wih0, Whh0, bih0, bhh0, Wih1, Whh1, bih1, bhh1,
                           W1, b1, W2, b2, out);
    }
}

// Round 5
// 408.635 us; speedup vs baseline: 1.1277x; 1.0935x over previous
//
#include <hip/hip_runtime.h>

#define T       512
#define DIN     32
#define HCELLS  64
#define NB      16      // batch elems per block (MFMA N dim)
#define NSLICE  64      // 1024 / NB
#define TB      256     // pipeline kernel: 4 waves (one layer per block)
#define CH      16      // chunk steps per cross-block handoff
#define NCH     (T / CH)

typedef _Float16 half8  __attribute__((ext_vector_type(8)));
typedef _Float16 half4v __attribute__((ext_vector_type(4)));
typedef float    float4v __attribute__((ext_vector_type(4)));

#define STRH    72      // h rows: 64 + 8 pad (halfs)
#define SB_HALFS (2*16*STRH)        // one layer's double-buffered h state

#define LOG2E   1.44269504f
#define SLOG2E  2.88539008f     // 2*log2(e); cell state kept as cs = SLOG2E * c

// Raw barrier (fallback kernel only).
#define BARRIER() asm volatile("s_waitcnt lgkmcnt(0)\n\ts_barrier" ::: "memory")

// ---- LDS flag sync (replaces per-step s_barrier in the pipeline kernel) ----
// Post: own h ds_write retired (lgkmcnt(0)) -> relaxed flag store.
// Wait: spin until all 4 waves completed step `need`-1 (flag >= need), then
// fence so the following ds_reads can't be hoisted above the check.
#define FLAG_POST(val) do { \
    asm volatile("s_waitcnt lgkmcnt(0)" ::: "memory"); \
    __hip_atomic_store(&FL[wl], (val), __ATOMIC_RELAXED, __HIP_MEMORY_SCOPE_WORKGROUP); \
} while (0)

#define FLAG_WAIT(need) do { \
    for (;;) { \
        int f0_ = __hip_atomic_load(&FL[0], __ATOMIC_RELAXED, __HIP_MEMORY_SCOPE_WORKGROUP); \
        int f1_ = __hip_atomic_load(&FL[1], __ATOMIC_RELAXED, __HIP_MEMORY_SCOPE_WORKGROUP); \
        int f2_ = __hip_atomic_load(&FL[2], __ATOMIC_RELAXED, __HIP_MEMORY_SCOPE_WORKGROUP); \
        int f3_ = __hip_atomic_load(&FL[3], __ATOMIC_RELAXED, __HIP_MEMORY_SCOPE_WORKGROUP); \
        if (f0_ >= (need) && f1_ >= (need) && f2_ >= (need) && f3_ >= (need)) break; \
    } \
    asm volatile("s_waitcnt lgkmcnt(0)" ::: "memory"); \
    __builtin_amdgcn_sched_barrier(0); \
} while (0)

// workspace layout
#define WS_FLAG_BYTES 4096
#define H0T   (16 * HCELLS)                  // halfs per step per slice
#define H0S   ((size_t)T * H0T)              // halfs per slice
#define WS_NEED (WS_FLAG_BYTES + (size_t)NSLICE * H0S * sizeof(_Float16))

__device__ __forceinline__ int hidx(int p, int n, int k) { return (p * 16 + n) * STRH + k; }

__device__ __forceinline__ void cvt8(const float* v, half8& hi) {
    #pragma unroll
    for (int e = 0; e < 8; ++e) hi[e] = (_Float16)v[e];
}

// Scaled-domain LSTM cell update, stage-major (SoA) over the 4 rows.
__device__ __forceinline__ void cell_vec(float4v z0, float4v z1, float4v z2, float4v z3,
                                         float4v& cs, half4v& hh, float4v* hout)
{
    float4v ei, ef, G2, eo, rFP, C2, rOC;
    #pragma unroll
    for (int r = 0; r < 4; ++r) ei[r] = __builtin_amdgcn_exp2f(z0[r]);   // e^{-zi}
    #pragma unroll
    for (int r = 0; r < 4; ++r) ef[r] = __builtin_amdgcn_exp2f(z1[r]);   // e^{-zf}
    #pragma unroll
    for (int r = 0; r < 4; ++r) G2[r] = __builtin_amdgcn_exp2f(z2[r]);   // e^{2 zg}
    #pragma unroll
    for (int r = 0; r < 4; ++r) eo[r] = __builtin_amdgcn_exp2f(z3[r]);   // e^{-zo}

    float4v I  = 1.0f + ei;
    float4v F  = 1.0f + ef;
    float4v Gp = 1.0f + G2;
    float4v P  = I * Gp;
    float4v FP = F * P;
    #pragma unroll
    for (int r = 0; r < 4; ++r) rFP[r] = __builtin_amdgcn_rcpf(FP[r]);

    float4v Gms, num, csn;
    #pragma unroll
    for (int r = 0; r < 4; ++r) Gms[r] = fmaf(SLOG2E, G2[r], -SLOG2E);
    #pragma unroll
    for (int r = 0; r < 4; ++r) num[r] = fmaf(F[r], Gms[r], cs[r] * P[r]);
    csn = num * rFP;
    #pragma unroll
    for (int r = 0; r < 4; ++r) csn[r] = fminf(fmaxf(csn[r], -50.0f), 50.0f);
    cs = csn;

    #pragma unroll
    for (int r = 0; r < 4; ++r) C2[r] = __builtin_amdgcn_exp2f(csn[r]);
    float4v O   = 1.0f + eo;
    float4v OCp = O * (1.0f + C2);
    #pragma unroll
    for (int r = 0; r < 4; ++r) rOC[r] = __builtin_amdgcn_rcpf(OCp[r]);
    float4v h = (C2 - 1.0f) * rOC;
    if (hout) *hout = h;
    #pragma unroll
    for (int r = 0; r < 4; ++r) hh[r] = (_Float16)h[r];
}

// ======================= pipelined 2-stage kernel (128 blocks) =======================
__global__ void __launch_bounds__(TB, 1)
lstm2_pipe_kernel(const float* __restrict__ x,
                  const float* __restrict__ Wih0, const float* __restrict__ Whh0,
                  const float* __restrict__ bih0, const float* __restrict__ bhh0,
                  const float* __restrict__ Wih1, const float* __restrict__ Whh1,
                  const float* __restrict__ bih1, const float* __restrict__ bhh1,
                  const float* __restrict__ W1,   const float* __restrict__ b1,
                  const float* __restrict__ W2,   const float* __restrict__ b2,
                  unsigned* __restrict__ prog, _Float16* __restrict__ h0g,
                  float* __restrict__ out)
{
    const int tid  = threadIdx.x;
    const int wl   = tid >> 6;          // wave 0..3: hidden slice wl*16..wl*16+15
    const int lane = tid & 63;
    const int n16  = lane & 15;         // MFMA free index / local batch
    const int q    = lane >> 4;         // quad 0..3
    const int j0   = wl * 16 + q * 4;   // hidden-unit base (4 rows)

    const int g     = blockIdx.x;
    const int role  = (g >> 3) & 1;
    const int slice = ((g >> 4) << 3) | (g & 7);
    const int b0    = slice * NB;

    __shared__ __align__(16) _Float16 SB[SB_HALFS];
    __shared__ __align__(16) float HS[16 * 68 + 16 * 33];
    __shared__ int FL[4];

    const float gsc[4] = {-LOG2E, -LOG2E, SLOG2E, -LOG2E};

    // ---------------- per-role weight fragments (single fp16) ----------------
    half8 ah[4][4];
    float4v biasv[4];

    #pragma unroll
    for (int l = 0; l < 4; ++l) {
        const int row = (l * 4 + wl) * 16 + n16;
        const float g2 = gsc[l];
        float v[8];
        if (role == 0) {
            {
                const float4* p = (const float4*)(Wih0 + row * DIN + q * 8);
                float4 u0 = p[0], u1 = p[1];
                v[0]=g2*u0.x; v[1]=g2*u0.y; v[2]=g2*u0.z; v[3]=g2*u0.w;
                v[4]=g2*u1.x; v[5]=g2*u1.y; v[6]=g2*u1.z; v[7]=g2*u1.w;
                cvt8(v, ah[l][0]);
            }
            #pragma unroll
            for (int kt = 1; kt < 3; ++kt) {
                const float4* p = (const float4*)(Whh0 + row * HCELLS + (kt - 1) * 32 + q * 8);
                float4 u0 = p[0], u1 = p[1];
                v[0]=g2*u0.x; v[1]=g2*u0.y; v[2]=g2*u0.z; v[3]=g2*u0.w;
                v[4]=g2*u1.x; v[5]=g2*u1.y; v[6]=g2*u1.z; v[7]=g2*u1.w;
                cvt8(v, ah[l][kt]);
            }
            const int r0 = l * 64 + j0;
            float4v bi = *(const float4v*)(bih0 + r0);
            float4v bh = *(const float4v*)(bhh0 + r0);
            biasv[l] = (bi + bh) * g2;
        } else {
            #pragma unroll
            for (int kt = 0; kt < 4; ++kt) {
                const float* base = (kt < 2) ? (Wih1 + row * HCELLS + kt * 32)
                                             : (Whh1 + row * HCELLS + (kt - 2) * 32);
                const float4* p = (const float4*)(base + q * 8);
                float4 u0 = p[0], u1 = p[1];
                v[0]=g2*u0.x; v[1]=g2*u0.y; v[2]=g2*u0.z; v[3]=g2*u0.w;
                v[4]=g2*u1.x; v[5]=g2*u1.y; v[6]=g2*u1.z; v[7]=g2*u1.w;
                cvt8(v, ah[l][kt]);
            }
            const int r0 = l * 64 + j0;
            float4v bi = *(const float4v*)(bih1 + r0);
            float4v bh = *(const float4v*)(bhh1 + r0);
            biasv[l] = (bi + bh) * g2;
        }
    }

    // zero the h double-buffer (h(-1) = 0) and flags
    for (int i = tid; i < SB_HALFS / 2; i += TB) ((int*)SB)[i] = 0;
    if (tid < 4) FL[tid] = 0;
    __syncthreads();

    float4v cs4 = {0.f, 0.f, 0.f, 0.f};
    float4v hl4;

    if (role == 0) {
        // ======================= producer: layer 0 =======================
        // 2-step-deep x prefetch ring (covers HBM-miss latency off the chain)
        const float* xq = x + ((size_t)(b0 + n16) * T) * DIN + q * 8;
        float4 xn0 = ((const float4*)xq)[0];
        float4 xn1 = ((const float4*)xq)[1];
        float4 xm0 = ((const float4*)(xq + DIN))[0];
        float4 xm1 = ((const float4*)(xq + DIN))[1];
        xq += 2 * DIN;

        _Float16* hstream = h0g + (size_t)slice * H0S + n16 * HCELLS + j0;

        #pragma unroll 2
        for (int t = 0; t < T; ++t) {
            const int pr = t & 1, pw = pr ^ 1;

            float4 xc0 = xn0, xc1 = xn1;
            xn0 = xm0; xn1 = xm1;
            if (t + 2 < T) { xm0 = ((const float4*)xq)[0]; xm1 = ((const float4*)xq)[1]; xq += DIN; }

            half8 bhx;
            bhx[0]=(_Float16)xc0.x; bhx[1]=(_Float16)xc0.y; bhx[2]=(_Float16)xc0.z; bhx[3]=(_Float16)xc0.w;
            bhx[4]=(_Float16)xc1.x; bhx[5]=(_Float16)xc1.y; bhx[6]=(_Float16)xc1.z; bhx[7]=(_Float16)xc1.w;

            // pre-wait: bias + x-part (no LDS dependence)
            float4v acc[4];
            #pragma unroll
            for (int l = 0; l < 4; ++l)
                acc[l] = __builtin_amdgcn_mfma_f32_16x16x32_f16(ah[l][0], bhx, biasv[l], 0, 0, 0);

            FLAG_WAIT(t);   // all waves wrote h0(t-1)

            half8 bh0a = *(const half8*)&SB[hidx(pr, n16, q * 8)];
            half8 bh0b = *(const half8*)&SB[hidx(pr, n16, 32 + q * 8)];
            #pragma unroll
            for (int l = 0; l < 4; ++l)
                acc[l] = __builtin_amdgcn_mfma_f32_16x16x32_f16(ah[l][1], bh0a, acc[l], 0, 0, 0);
            #pragma unroll
            for (int l = 0; l < 4; ++l)
                acc[l] = __builtin_amdgcn_mfma_f32_16x16x32_f16(ah[l][2], bh0b, acc[l], 0, 0, 0);

            half4v hh;
            cell_vec(acc[0], acc[1], acc[2], acc[3], cs4, hh, nullptr);
            *(half4v*)&SB[hidx(pw, n16, j0)] = hh;                 // LDS for own recurrence
            *(half4v*)(hstream + (size_t)t * H0T) = hh;            // global stream for L1

            FLAG_POST(t + 1);

            if ((t & (CH - 1)) == (CH - 1)) {
                __syncthreads();   // drains vmcnt(0): all waves' h0 stores complete
                if (tid == 0)
                    __hip_atomic_store(prog + slice, (unsigned)(t / CH + 1),
                                       __ATOMIC_RELEASE, __HIP_MEMORY_SCOPE_AGENT);
            }
        }
        return;   // producer blocks exit; consumer writes out
    }

    // ======================= consumer: layer 1 + head =======================
    const _Float16* gbase = h0g + (size_t)slice * H0S + n16 * HCELLS;
    const int ka = q * 8, kb = 32 + q * 8;

    half8 a_cur, b_cur;
    for (int c = 0; c < NCH; ++c) {
        if (tid == 0) {
            unsigned v;
            while ((v = __hip_atomic_load(prog + slice, __ATOMIC_ACQUIRE,
                                          __HIP_MEMORY_SCOPE_AGENT)) < (unsigned)(c + 1))
                __builtin_amdgcn_s_sleep(2);
        }
        __syncthreads();   // all waves' loads below are ordered after the acquire+inv

        {
            const _Float16* p0 = gbase + (size_t)(c * CH) * H0T;
            a_cur = *(const half8*)(p0 + ka);
            b_cur = *(const half8*)(p0 + kb);
        }

        #pragma unroll 2
        for (int i = 0; i < CH; ++i) {
            const int t = c * CH + i;
            const int sr = (i + 1) & 1;   // slot holding h1(t-1)
            const int sw = i & 1;

            half8 a_nxt, b_nxt;
            if (i + 1 < CH) {   // never prefetch past the published chunk
                const _Float16* pn = gbase + (size_t)(t + 1) * H0T;
                a_nxt = *(const half8*)(pn + ka);
                b_nxt = *(const half8*)(pn + kb);
            }

            // pre-wait: bias + global-h0 part (no LDS dependence)
            float4v acc[4];
            #pragma unroll
            for (int l = 0; l < 4; ++l)
                acc[l] = __builtin_amdgcn_mfma_f32_16x16x32_f16(ah[l][0], a_cur, biasv[l], 0, 0, 0);
            #pragma unroll
            for (int l = 0; l < 4; ++l)
                acc[l] = __builtin_amdgcn_mfma_f32_16x16x32_f16(ah[l][1], b_cur, acc[l], 0, 0, 0);

            FLAG_WAIT(t);   // all waves wrote h1(t-1)

            half8 c1 = *(const half8*)&SB[hidx(sr, n16, q * 8)];
            half8 c2 = *(const half8*)&SB[hidx(sr, n16, 32 + q * 8)];
            #pragma unroll
            for (int l = 0; l < 4; ++l)
                acc[l] = __builtin_amdgcn_mfma_f32_16x16x32_f16(ah[l][2], c1, acc[l], 0, 0, 0);
            #pragma unroll
            for (int l = 0; l < 4; ++l)
                acc[l] = __builtin_amdgcn_mfma_f32_16x16x32_f16(ah[l][3], c2, acc[l], 0, 0, 0);

            half4v hh;
            cell_vec(acc[0], acc[1], acc[2], acc[3], cs4, hh, &hl4);
            *(half4v*)&SB[hidx(sw, n16, j0)] = hh;

            FLAG_POST(t + 1);

            a_cur = a_nxt; b_cur = b_nxt;
        }
    }

    // ---------------- head: relu(h1 @ W1^T + b1) @ W2^T + b2 ----------------
    float* h1f = HS;             // [16][68]
    float* hid = HS + 16 * 68;   // [16][33]
    *(float4v*)&h1f[n16 * 68 + j0] = hl4;
    __syncthreads();

    {
        const int n2 = tid >> 4, m = tid & 15;
        float s0 = b1[m], s1 = b1[m + 16];
        const float* w0p = W1 + m * HCELLS;
        const float* w1p = W1 + (m + 16) * HCELLS;
        #pragma unroll
        for (int j = 0; j < HCELLS; ++j) {
            float hv = h1f[n2 * 68 + j];
            s0 = fmaf(w0p[j], hv, s0);
            s1 = fmaf(w1p[j], hv, s1);
        }
        hid[n2 * 33 + m]      = fmaxf(s0, 0.0f);
        hid[n2 * 33 + m + 16] = fmaxf(s1, 0.0f);
    }
    __syncthreads();

    if (tid < NB) {
        float s = b2[0];
        #pragma unroll
        for (int m = 0; m < 32; ++m) s = fmaf(W2[m], hid[tid * 33 + m], s);
        out[b0 + tid] = s;
    }
}

// ======================= fallback: verified round-2 single-grid kernel =======================
#define TBF     512
#define FB_H0   0
#define FB_H1   (2*16*STRH)
#define FB_HALFS (FB_H1 + 2*16*STRH)

__device__ __forceinline__ void cell_update(const float4v acc[4], float* cs,
                                            half4v& hh, float* hout)
{
    #pragma unroll
    for (int r = 0; r < 4; ++r) {
        float ei = __builtin_amdgcn_exp2f(acc[0][r]);
        float ef = __builtin_amdgcn_exp2f(acc[1][r]);
        float G2 = __builtin_amdgcn_exp2f(acc[2][r]);
        float I  = 1.0f + ei, F = 1.0f + ef;
        float Gp = 1.0f + G2;
        float Gms = fmaf(SLOG2E, G2, -SLOG2E);
        float P   = I * Gp;
        float num = fmaf(F, Gms, cs[r] * P);
        float csn = num * __builtin_amdgcn_rcpf(F * P);
        csn = fminf(fmaxf(csn, -50.0f), 50.0f);
        cs[r] = csn;
        float eo = __builtin_amdgcn_exp2f(acc[3][r]);
        float C2 = __builtin_amdgcn_exp2f(csn);
        float O  = 1.0f + eo;
        float Cp = 1.0f + C2, Cm = C2 - 1.0f;
        float h  = Cm * __builtin_amdgcn_rcpf(O * Cp);
        if (hout) hout[r] = h;
        hh[r] = (_Float16)h;
    }
}

__global__ void __launch_bounds__(TBF, 2)
lstm2_mfma_fallback(const float* __restrict__ x,
                    const float* __restrict__ Wih0, const float* __restrict__ Whh0,
                    const float* __restrict__ bih0, const float* __restrict__ bhh0,
                    const float* __restrict__ Wih1, const float* __restrict__ Whh1,
                    const float* __restrict__ bih1, const float* __restrict__ bhh1,
                    const float* __restrict__ W1,   const float* __restrict__ b1,
                    const float* __restrict__ W2,   const float* __restrict__ b2,
                    float* __restrict__ out)
{
    const int tid  = threadIdx.x;
    const int wid  = tid >> 6;
    const int grp  = wid >> 2;
    const int wl   = wid & 3;
    const int lane = tid & 63;
    const int n16  = lane & 15;
    const int q    = lane >> 4;
    const int j0   = wl * 16 + q * 4;
    const int b0   = blockIdx.x * NB;

    __shared__ __align__(16) _Float16 SB[FB_HALFS];
    __shared__ __align__(16) float HS[16 * 68 + 16 * 33];

    const float gsc[4] = {-LOG2E, -LOG2E, SLOG2E, -LOG2E};
    half8 ah[4][4];
    float4v biasv[4];

    #pragma unroll
    for (int l = 0; l < 4; ++l) {
        const int row = (l * 4 + wl) * 16 + n16;
        const float g = gsc[l];
        float v[8];
        if (grp == 0) {
            {
                const float4* p = (const float4*)(Wih0 + row * DIN + q * 8);
                float4 u0 = p[0], u1 = p[1];
                v[0]=g*u0.x; v[1]=g*u0.y; v[2]=g*u0.z; v[3]=g*u0.w;
                v[4]=g*u1.x; v[5]=g*u1.y; v[6]=g*u1.z; v[7]=g*u1.w;
                cvt8(v, ah[l][0]);
            }
            #pragma unroll
            for (int kt = 1; kt < 3; ++kt) {
                const float4* p = (const float4*)(Whh0 + row * HCELLS + (kt - 1) * 32 + q * 8);
                float4 u0 = p[0], u1 = p[1];
                v[0]=g*u0.x; v[1]=g*u0.y; v[2]=g*u0.z; v[3]=g*u0.w;
                v[4]=g*u1.x; v[5]=g*u1.y; v[6]=g*u1.z; v[7]=g*u1.w;
                cvt8(v, ah[l][kt]);
            }
            const int r0 = l * 64 + j0;
            float4v bi = *(const float4v*)(bih0 + r0);
            float4v bh = *(const float4v*)(bhh0 + r0);
            biasv[l] = (bi + bh) * g;
        } else {
            #pragma unroll
            for (int kt = 0; kt < 4; ++kt) {
                const float* base = (kt < 2) ? (Wih1 + row * HCELLS + kt * 32)
                                             : (Whh1 + row * HCELLS + (kt - 2) * 32);
                const float4* p = (const float4*)(base + q * 8);
                float4 u0 = p[0], u1 = p[1];
                v[0]=g*u0.x; v[1]=g*u0.y; v[2]=g*u0.z; v[3]=g*u0.w;
                v[4]=g*u1.x; v[5]=g*u1.y; v[6]=g*u1.z; v[7]=g*u1.w;
                cvt8(v, ah[l][kt]);
            }
            const int r0 = l * 64 + j0;
            float4v bi = *(const float4v*)(bih1 + r0);
            float4v bh = *(const float4v*)(bhh1 + r0);
            biasv[l] = (bi + bh) * g;
        }
    }

    for (int i = tid; i < FB_HALFS / 2; i += TBF) ((int*)SB)[i] = 0;

    const float* xq = nullptr;
    float4 xn0, xn1;
    if (grp == 0) {
        xq = x + ((size_t)(b0 + n16) * T) * DIN + q * 8;
        xn0 = *(const float4*)xq;
        xn1 = *(const float4*)(xq + 4);
        xq += DIN;
    }
    __syncthreads();

    float cs[4] = {0, 0, 0, 0};
    float hlast[4];

    #pragma unroll 2
    for (int t = 0; t < T; ++t) {
        const int pr = t & 1, pw = pr ^ 1;
        if (grp == 0) {
            float4 xc0 = xn0, xc1 = xn1;
            if (t + 1 < T) { xn0 = *(const float4*)xq; xn1 = *(const float4*)(xq + 4); xq += DIN; }
            half8 bhx;
            bhx[0]=(_Float16)xc0.x; bhx[1]=(_Float16)xc0.y; bhx[2]=(_Float16)xc0.z; bhx[3]=(_Float16)xc0.w;
            bhx[4]=(_Float16)xc1.x; bhx[5]=(_Float16)xc1.y; bhx[6]=(_Float16)xc1.z; bhx[7]=(_Float16)xc1.w;
            float4v acc[4];
            #pragma unroll
            for (int l = 0; l < 4; ++l)
                acc[l] = __builtin_amdgcn_mfma_f32_16x16x32_f16(ah[l][0], bhx, biasv[l], 0, 0, 0);
            #pragma unroll
            for (int kt = 1; kt < 3; ++kt) {
                half8 bh = *(const half8*)&SB[FB_H0 + hidx(pr, n16, (kt - 1) * 32 + q * 8)];
                #pragma unroll
                for (int l = 0; l < 4; ++l)
                    acc[l] = __builtin_amdgcn_mfma_f32_16x16x32_f16(ah[l][kt], bh, acc[l], 0, 0, 0);
            }
            half4v hh;
            cell_update(acc, cs, hh, nullptr);
            *(half4v*)&SB[FB_H0 + hidx(pw, n16, j0)] = hh;
        } else if (t > 0) {
            float4v acc[4];
            #pragma unroll
            for (int l = 0; l < 4; ++l) acc[l] = biasv[l];
            #pragma unroll
            for (int kt = 0; kt < 4; ++kt) {
                half8 bh = (kt < 2)
                    ? *(const half8*)&SB[FB_H0 + hidx(pr, n16, kt * 32 + q * 8)]
                    : *(const half8*)&SB[FB_H1 + hidx(pw, n16, (kt - 2) * 32 + q * 8)];
                #pragma unroll
                for (int l = 0; l < 4; ++l)
                    acc[l] = __builtin_amdgcn_mfma_f32_16x16x32_f16(ah[l][kt], bh, acc[l], 0, 0, 0);
            }
            half4v hh;
            cell_update(acc, cs, hh, nullptr);
            *(half4v*)&SB[FB_H1 + hidx(pr, n16, j0)] = hh;
        }
        BARRIER();
    }

    float* h1f = HS;
    float* hid = HS + 16 * 68;
    if (grp == 1) {
        float4v acc[4];
        #pragma unroll
        for (int l = 0; l < 4; ++l) acc[l] = biasv[l];
        #pragma unroll
        for (int kt = 0; kt < 4; ++kt) {
            half8 bh = (kt < 2)
                ? *(const half8*)&SB[FB_H0 + hidx(0, n16, kt * 32 + q * 8)]
                : *(const half8*)&SB[FB_H1 + hidx(1, n16, (kt - 2) * 32 + q * 8)];
            #pragma unroll
            for (int l = 0; l < 4; ++l)
                acc[l] = __builtin_amdgcn_mfma_f32_16x16x32_f16(ah[l][kt], bh, acc[l], 0, 0, 0);
        }
        half4v hh;
        cell_update(acc, cs, hh, hlast);
        *(float4*)&h1f[n16 * 68 + j0] = *(const float4*)hlast;
    }
    __syncthreads();

    if (tid < 256) {
        const int n2 = tid >> 4, m = tid & 15;
        float s0 = b1[m], s1 = b1[m + 16];
        const float* w0p = W1 + m * HCELLS;
        const float* w1p = W1 + (m + 16) * HCELLS;
        #pragma unroll
        for (int j = 0; j < HCELLS; ++j) {
            float hv = h1f[n2 * 68 + j];
            s0 = fmaf(w0p[j], hv, s0);
            s1 = fmaf(w1p[j], hv, s1);
        }
        hid[n2 * 33 + m]      = fmaxf(s0, 0.0f);
        hid[n2 * 33 + m + 16] = fmaxf(s1, 0.0f);
    }
    __syncthreads();

    if (tid < NB) {
        float s = b2[0];
        #pragma unroll
        for (int m = 0; m < 32; ++m) s = fmaf(W2[m], hid[tid * 33 + m], s);
        out[b0 + tid] = s;
    }
}

extern "C" void kernel_launch(void* const* d_in, const int* in_sizes, int n_in,
                              void* d_out, int out_size, void* d_ws, size_t ws_size,
                              hipStream_t stream) {
    const float* x    = (const float*)d_in[0];
    const float* Wih0 = (const float*)d_in[1];
    const float* Whh0 = (const float*)d_in[2];
    const float* bih0 = (const float*)d_in[3];
    const float* bhh0 = (const float*)d_in[4];
    const float* Wih1 = (const float*)d_in[5];
    const float* Whh1 = (const float*)d_in[6];
    const float* bih1 = (const float*)d_in[7];
    const float* bhh1 = (const float*)d_in[8];
    const float* W1   = (const float*)d_in[9];
    const float* b1   = (const float*)d_in[10];
    const float* W2   = (const float*)d_in[11];
    const float* b2   = (const float*)d_in[12];
    float* out = (float*)d_out;

    if (d_ws != nullptr && ws_size >= WS_NEED) {
        hipMemsetAsync(d_ws, 0, WS_FLAG_BYTES, stream);   // reset progress flags each launch
        unsigned*  prog = (unsigned*)d_ws;
        _Float16*  h0g  = (_Float16*)((char*)d_ws + WS_FLAG_BYTES);
        hipLaunchKernelGGL(lstm2_pipe_kernel, dim3(2 * NSLICE), dim3(TB), 0, stream,
                           x, Wih0, Whh0, bih0, bhh0, Wih1, Whh1, bih1, bhh1,
                           W1, b1, W2, b2, prog, h0g, out);
    } else {
        hipLaunchKernelGGL(lstm2_mfma_fallback, dim3(NSLICE), dim3(TBF), 0, stream,
                           x, Wih0, Whh0, bih0, bhh0, Wih1, Whh1, bih1, bhh1,
                           W1, b1, W2, b2, out);
    }
}